// Round 7
// baseline (342.057 us; speedup 1.0000x reference)
//
#include <hip/hip_runtime.h>

typedef __bf16 bf16;
typedef __bf16 bf16x4 __attribute__((ext_vector_type(4)));
typedef __bf16 bf16x8 __attribute__((ext_vector_type(8)));
typedef float f32x4 __attribute__((ext_vector_type(4)));

__device__ __forceinline__ f32x4 MFMA16(bf16x8 a, bf16x8 b, f32x4 c) {
  return __builtin_amdgcn_mfma_f32_16x16x32_bf16(a, b, c, 0, 0, 0);
}

__device__ __forceinline__ bf16 split_hi(float v) { return (bf16)v; }
__device__ __forceinline__ bf16 split_lo(float v) { return (bf16)(v - (float)(bf16)v); }

// ---- fused prep v2: build Wc/Wn tiles in-block, transpose+split in LDS, and
// write WcT/WnT bf16 pairs DIRECTLY (no Wc/Wn f32 intermediates, k_transp
// kernel deleted). [0,256): Wc tiles; [256,1024): Wn tiles; [1024,2048): cvt.
__global__ void k_prep(const float* __restrict__ WO, bf16* __restrict__ WOb,
                       const float* __restrict__ neurons, const float* __restrict__ cw,
                       const int* __restrict__ cidx, bf16* __restrict__ WcTh,
                       bf16* __restrict__ WcTl, const float* __restrict__ pool,
                       const float* __restrict__ wq, const int* __restrict__ iq,
                       const float* __restrict__ wk, const int* __restrict__ ik,
                       const float* __restrict__ wv, const int* __restrict__ iv,
                       bf16* __restrict__ Wth, bf16* __restrict__ Wtl) {
  const int bid = blockIdx.x, tid = threadIdx.x;
  if (bid >= 1024) {  // W_O f32 -> bf16
    const long i = ((long)(bid - 1024) * 256 + tid) * 4;
    const f32x4 v = *(const f32x4*)&WO[i];
    bf16x4 o;
#pragma unroll
    for (int j = 0; j < 4; ++j) o[j] = (bf16)v[j];
    *(bf16x4*)&WOb[i] = o;
    return;
  }
  __shared__ float t[64][65];
  bf16 *outh, *outl;
  int M, n0, m0;
  // compute this block's 64x64 tile of the (pre-transpose) matrix into t
  {
    const int rr = tid >> 2;               // in-tile row
    const int cb = (tid & 3) * 16;         // in-tile col base (16 cols/thread)
    float acc[16];
#pragma unroll
    for (int j = 0; j < 16; ++j) acc[j] = 0.f;
    if (bid < 256) {  // Wc[b][d][r], M=1024(d) N=128(r)
      const int z = bid >> 5, rem = bid & 31;
      n0 = (rem >> 4) * 64;
      m0 = (rem & 15) * 64;
      M = 1024;
      outh = WcTh + (long)z * 131072;
      outl = WcTl + (long)z * 131072;
#pragma unroll
      for (int k = 0; k < 16; ++k) {
        const float wkk = cw[z * 16 + k];
        const int ni = cidx[z * 16 + k];
        const float* src = &neurons[((long)ni * 1024 + m0 + rr) * 128 + n0 + cb];
#pragma unroll
        for (int q = 0; q < 4; ++q) {
          const f32x4 v = *(const f32x4*)&src[q * 4];
#pragma unroll
          for (int j = 0; j < 4; ++j) acc[q * 4 + j] += wkk * v[j];
        }
      }
    } else {  // Wn[z][r][d], M=128(r) N=1024(d)
      const int tt = bid - 256;
      const int z = tt >> 5, rem = tt & 31;
      n0 = (rem & 15) * 64;
      m0 = (rem >> 4) * 64;
      M = 128;
      outh = Wth + (long)z * 131072;
      outl = Wtl + (long)z * 131072;
      const int which = z >> 3, b = z & 7;
      const float* wp = which == 0 ? wq : (which == 1 ? wk : wv);
      const int* ip = which == 0 ? iq : (which == 1 ? ik : iv);
#pragma unroll
      for (int k = 0; k < 8; ++k) {
        const float wkk = wp[b * 8 + k];
        const int ni = ip[b * 8 + k];
        const float* src = &pool[((long)ni * 128 + m0 + rr) * 1024 + n0 + cb];
#pragma unroll
        for (int q = 0; q < 4; ++q) {
          const f32x4 v = *(const f32x4*)&src[q * 4];
#pragma unroll
          for (int j = 0; j < 4; ++j) acc[q * 4 + j] += wkk * v[j];
        }
      }
    }
#pragma unroll
    for (int j = 0; j < 16; ++j) t[rr][cb + j] = acc[j];
  }
  __syncthreads();
  // transpose-split epilogue (identical to old k_transp phase 2)
#pragma unroll
  for (int i = 0; i < 16; ++i) {
    const int lin = i * 256 + tid;
    const int r = lin >> 6, c = lin & 63;
    const float v = t[c][r];
    const long off = (long)(n0 + r) * M + (m0 + c);
    outh[off] = split_hi(v);
    outl[off] = split_lo(v);
  }
}

// ---- h-GEMM: A f32 (split in-kernel), Bt pre-split bf16 pair; out split-pair.
// A [M][K] f32, Bt[n][k] pair. M=1024 N=128 K=1024. BM=BN=64, 4 waves 2x2.
__global__ __launch_bounds__(256) void k_gemm_h(
    const float* __restrict__ A, const bf16* __restrict__ Bth,
    const bf16* __restrict__ Btl, bf16* __restrict__ Ch, bf16* __restrict__ Cl,
    int M, int N, int K, long sA, long sB, long sC) {
  constexpr int LDR = 40;
  __shared__ __align__(16) bf16 Ash[64 * LDR], Asl[64 * LDR];
  __shared__ __align__(16) bf16 Bsh[64 * LDR], Bsl[64 * LDR];
  const int tid = threadIdx.x, wave = tid >> 6, lane = tid & 63;
  const int quad = lane >> 4, l16 = lane & 15;
  const int wrow = wave >> 1, wcol = wave & 1;
  const int z = blockIdx.z;
  const float* Ap = A + (long)z * sA;
  const bf16* Bph = Bth + (long)z * sB;
  const bf16* Bpl = Btl + (long)z * sB;
  const long m0 = (long)blockIdx.y * 64, n0 = (long)blockIdx.x * 64;
  f32x4 acc[2][2];
#pragma unroll
  for (int mt = 0; mt < 2; ++mt)
#pragma unroll
    for (int nt = 0; nt < 2; ++nt) acc[mt][nt] = (f32x4){0.f, 0.f, 0.f, 0.f};
  for (int k0 = 0; k0 < K; k0 += 32) {
#pragma unroll
    for (int i = 0; i < 2; ++i) {
      const int c = i * 256 + tid, r = c >> 3, c4 = c & 7;
      const f32x4 v = *(const f32x4*)&Ap[(m0 + r) * K + k0 + c4 * 4];
      bf16x4 h4, l4;
#pragma unroll
      for (int j = 0; j < 4; ++j) { h4[j] = split_hi(v[j]); l4[j] = split_lo(v[j]); }
      *(bf16x4*)&Ash[r * LDR + c4 * 4] = h4;
      *(bf16x4*)&Asl[r * LDR + c4 * 4] = l4;
    }
    {
      const int r = tid >> 2, c8 = tid & 3;
      *(bf16x8*)&Bsh[r * LDR + c8 * 8] = *(const bf16x8*)&Bph[(n0 + r) * K + k0 + c8 * 8];
      *(bf16x8*)&Bsl[r * LDR + c8 * 8] = *(const bf16x8*)&Bpl[(n0 + r) * K + k0 + c8 * 8];
    }
    __syncthreads();
    bf16x8 ah[2], al[2], bh[2], bl[2];
#pragma unroll
    for (int mt = 0; mt < 2; ++mt) {
      const int row = wrow * 32 + mt * 16 + l16;
      ah[mt] = *(const bf16x8*)&Ash[row * LDR + quad * 8];
      al[mt] = *(const bf16x8*)&Asl[row * LDR + quad * 8];
    }
#pragma unroll
    for (int nt = 0; nt < 2; ++nt) {
      const int row = wcol * 32 + nt * 16 + l16;
      bh[nt] = *(const bf16x8*)&Bsh[row * LDR + quad * 8];
      bl[nt] = *(const bf16x8*)&Bsl[row * LDR + quad * 8];
    }
#pragma unroll
    for (int mt = 0; mt < 2; ++mt)
#pragma unroll
      for (int nt = 0; nt < 2; ++nt) {
        acc[mt][nt] = MFMA16(ah[mt], bh[nt], acc[mt][nt]);
        acc[mt][nt] = MFMA16(ah[mt], bl[nt], acc[mt][nt]);
        acc[mt][nt] = MFMA16(al[mt], bh[nt], acc[mt][nt]);
      }
    __syncthreads();
  }
#pragma unroll
  for (int mt = 0; mt < 2; ++mt)
#pragma unroll
    for (int nt = 0; nt < 2; ++nt)
#pragma unroll
      for (int r = 0; r < 4; ++r) {
        const long row = m0 + wrow * 32 + mt * 16 + quad * 4 + r;
        const long col = n0 + wcol * 32 + nt * 16 + l16;
        const float v = acc[mt][nt][r];
        const long off = (long)z * sC + row * (long)N + col;
        const bf16 hi = (bf16)v;
        Ch[off] = hi;
        Cl[off] = (bf16)(v - (float)hi);
      }
}

// ---- fused Q/K/V projection GEMM v2: 128x128 tiles (m93 ladder step), one
// launch, grid (8,8,24). Per wave: 64x64 output = acc[4][4]; per k-step 16
// ds_read_b128 feed 48 MFMAs (sp) vs 64^2's 8:12 -- 3x better MFMA:DS ratio.
// z in [0,16): split-pair path (3 MFMAs), out (z<8?Q:K) split-pair head-split.
// z in [16,24): V^T path (1 MFMA), out Vt plain bf16 [b][d][s].
__global__ __launch_bounds__(256, 1) void k_gemm_qkv(
    const bf16* __restrict__ hh, const bf16* __restrict__ hl,
    const bf16* __restrict__ Wth, const bf16* __restrict__ Wtl,
    bf16* __restrict__ Qhi, bf16* __restrict__ Qlo, bf16* __restrict__ Khi,
    bf16* __restrict__ Klo, bf16* __restrict__ Vt, float qscale) {
  constexpr int LDR = 40, K = 128;
  __shared__ __align__(16) bf16 Ash[128 * LDR], Bsh[128 * LDR];
  __shared__ __align__(16) bf16 Asl[128 * LDR], Bsl[128 * LDR];
  const int tid = threadIdx.x, wave = tid >> 6, lane = tid & 63;
  const int quad = lane >> 4, l16 = lane & 15;
  const int wrow = wave >> 1, wcol = wave & 1;
  const int z = blockIdx.z;
  const bool sp = z < 16;
  const bf16 *Aph, *Apl, *Bph, *Bpl;
  bf16 *C, *C2;
  int heads;
  float scale;
  if (sp) {
    Aph = hh + ((long)(z & 7) << 17);
    Apl = hl + ((long)(z & 7) << 17);
    Bph = Wth + ((long)z << 17);
    Bpl = Wtl + ((long)z << 17);
    C = (z < 8 ? Qhi : Khi) + ((long)(z & 7) << 20);
    C2 = (z < 8 ? Qlo : Klo) + ((long)(z & 7) << 20);
    heads = 1;
    scale = z < 8 ? qscale : 1.f;
  } else {
    Aph = Wth + ((long)z << 17);
    Apl = nullptr;
    Bph = hh + ((long)(z - 16) << 17);
    Bpl = nullptr;
    C = Vt + ((long)(z - 16) << 20);
    C2 = nullptr;
    heads = 0;
    scale = 1.f;
  }
  const long m0 = (long)blockIdx.y * 128, n0 = (long)blockIdx.x * 128;
  f32x4 acc[4][4];
#pragma unroll
  for (int mt = 0; mt < 4; ++mt)
#pragma unroll
    for (int nt = 0; nt < 4; ++nt) acc[mt][nt] = (f32x4){0.f, 0.f, 0.f, 0.f};
  for (int k0 = 0; k0 < K; k0 += 32) {
#pragma unroll
    for (int i = 0; i < 2; ++i) {
      const int id = i * 256 + tid, r = id >> 2, c8 = id & 3;
      *(bf16x8*)&Ash[r * LDR + c8 * 8] = *(const bf16x8*)&Aph[(m0 + r) * K + k0 + c8 * 8];
      if (sp)
        *(bf16x8*)&Asl[r * LDR + c8 * 8] = *(const bf16x8*)&Apl[(m0 + r) * K + k0 + c8 * 8];
      *(bf16x8*)&Bsh[r * LDR + c8 * 8] = *(const bf16x8*)&Bph[(n0 + r) * K + k0 + c8 * 8];
      if (sp)
        *(bf16x8*)&Bsl[r * LDR + c8 * 8] = *(const bf16x8*)&Bpl[(n0 + r) * K + k0 + c8 * 8];
    }
    __syncthreads();
    bf16x8 ah[4], al[4], bh[4], bl[4];
#pragma unroll
    for (int mt = 0; mt < 4; ++mt) {
      const int row = wrow * 64 + mt * 16 + l16;
      ah[mt] = *(const bf16x8*)&Ash[row * LDR + quad * 8];
      if (sp) al[mt] = *(const bf16x8*)&Asl[row * LDR + quad * 8];
    }
#pragma unroll
    for (int nt = 0; nt < 4; ++nt) {
      const int row = wcol * 64 + nt * 16 + l16;
      bh[nt] = *(const bf16x8*)&Bsh[row * LDR + quad * 8];
      if (sp) bl[nt] = *(const bf16x8*)&Bsl[row * LDR + quad * 8];
    }
#pragma unroll
    for (int mt = 0; mt < 4; ++mt)
#pragma unroll
      for (int nt = 0; nt < 4; ++nt) {
        acc[mt][nt] = MFMA16(ah[mt], bh[nt], acc[mt][nt]);
        if (sp) {
          acc[mt][nt] = MFMA16(ah[mt], bl[nt], acc[mt][nt]);
          acc[mt][nt] = MFMA16(al[mt], bh[nt], acc[mt][nt]);
        }
      }
    __syncthreads();
  }
#pragma unroll
  for (int mt = 0; mt < 4; ++mt)
#pragma unroll
    for (int nt = 0; nt < 4; ++nt)
#pragma unroll
      for (int r = 0; r < 4; ++r) {
        const long row = m0 + wrow * 64 + mt * 16 + quad * 4 + r;
        const long col = n0 + wcol * 64 + nt * 16 + l16;
        const float v = acc[mt][nt][r] * scale;
        const long off = heads ? ((col >> 6) * ((long)1024 * 64) + row * 64 + (col & 63))
                               : (row * (long)1024 + col);
        if (sp) {
          const bf16 hi = (bf16)v;
          C[off] = hi;
          C2[off] = (bf16)(v - (float)hi);
        } else {
          C[off] = (bf16)v;
        }
      }
}

// ---- plain bf16 GEMM (output projection): C = A(MxK) * Bt[n][k], out f32. ----
template <int BM, int BN>
__global__ __launch_bounds__(256) void k_gemm_bt(
    const bf16* __restrict__ A, const bf16* __restrict__ Bt, float* __restrict__ C,
    int M, int N, int K) {
  constexpr int BK = 32, LDR = BK + 8;
  constexpr int MT = BM / 32, NT = BN / 32;
  __shared__ __align__(16) bf16 As[BM * LDR];
  __shared__ __align__(16) bf16 Bs[BN * LDR];
  const int tid = threadIdx.x, wave = tid >> 6, lane = tid & 63;
  const int quad = lane >> 4, l16 = lane & 15;
  const int wrow = wave >> 1, wcol = wave & 1;
  const long m0 = (long)blockIdx.y * BM, n0 = (long)blockIdx.x * BN;
  f32x4 acc[MT][NT];
#pragma unroll
  for (int mt = 0; mt < MT; ++mt)
#pragma unroll
    for (int nt = 0; nt < NT; ++nt) acc[mt][nt] = (f32x4){0.f, 0.f, 0.f, 0.f};
  constexpr int ACH = BM * BK / 8 / 256;
  constexpr int BCH = BN * BK / 8 / 256;
  for (int k0 = 0; k0 < K; k0 += BK) {
#pragma unroll
    for (int i = 0; i < ACH; ++i) {
      const int c = i * 256 + tid, r = c >> 2, c4 = c & 3;
      *(bf16x8*)&As[r * LDR + c4 * 8] = *(const bf16x8*)&A[(m0 + r) * K + k0 + c4 * 8];
    }
#pragma unroll
    for (int i = 0; i < BCH; ++i) {
      const int c = i * 256 + tid, r = c >> 2, c4 = c & 3;
      *(bf16x8*)&Bs[r * LDR + c4 * 8] = *(const bf16x8*)&Bt[(n0 + r) * K + k0 + c4 * 8];
    }
    __syncthreads();
    bf16x8 af[MT], bfr[NT];
#pragma unroll
    for (int mt = 0; mt < MT; ++mt)
      af[mt] = *(const bf16x8*)&As[(wrow * MT * 16 + mt * 16 + l16) * LDR + quad * 8];
#pragma unroll
    for (int nt = 0; nt < NT; ++nt)
      bfr[nt] = *(const bf16x8*)&Bs[(wcol * NT * 16 + nt * 16 + l16) * LDR + quad * 8];
#pragma unroll
    for (int mt = 0; mt < MT; ++mt)
#pragma unroll
      for (int nt = 0; nt < NT; ++nt)
        acc[mt][nt] = MFMA16(af[mt], bfr[nt], acc[mt][nt]);
    __syncthreads();
  }
#pragma unroll
  for (int mt = 0; mt < MT; ++mt)
#pragma unroll
    for (int nt = 0; nt < NT; ++nt)
#pragma unroll
      for (int r = 0; r < 4; ++r) {
        const long row = m0 + wrow * MT * 16 + mt * 16 + quad * 4 + r;
        const long col = n0 + wcol * NT * 16 + nt * 16 + l16;
        C[row * (long)N + col] = acc[mt][nt][r];
      }
}

// ---- causal flash attention v6 (unchanged this round; control kernel):
// swapped QK^T, in-register softmax, two strips/wave, shared K/V fragments.
__global__ __launch_bounds__(512, 2) void k_attn(
    const bf16* __restrict__ Qhi, const bf16* __restrict__ Qlo,
    const bf16* __restrict__ Khi, const bf16* __restrict__ Klo,
    const bf16* __restrict__ Vtg, bf16* __restrict__ Og) {
  __shared__ __align__(16) bf16 KhiS[2 * 64 * 72], KloS[2 * 64 * 72];
  __shared__ __align__(16) bf16 VtS[2 * 64 * 72];
  const int p = blockIdx.x, bh = blockIdx.y;
  const int b = bh >> 4, hh = bh & 15;
  const int tid = threadIdx.x, wave = tid >> 6, lane = tid & 63;
  const int quad = lane >> 4, l16 = lane & 15;
  const long bhS = (long)bh * 1024 * 64;
  const bf16* KhiG = Khi + bhS;
  const bf16* KloG = Klo + bhS;
  const bf16* VtG = Vtg + (long)bh * 64 * 1024;
  const int qbwA = p * 128 + wave * 16;
  const int qbwB = (7 - p) * 128 + wave * 16;
  bf16x8 qhA[2], qlA[2], qhB[2], qlB[2];
  {
    const long rA = (long)(qbwA + l16) * 64;
    const long rB = (long)(qbwB + l16) * 64;
#pragma unroll
    for (int s = 0; s < 2; ++s) {
      qhA[s] = *(const bf16x8*)&Qhi[bhS + rA + s * 32 + quad * 8];
      qlA[s] = *(const bf16x8*)&Qlo[bhS + rA + s * 32 + quad * 8];
      qhB[s] = *(const bf16x8*)&Qhi[bhS + rB + s * 32 + quad * 8];
      qlB[s] = *(const bf16x8*)&Qlo[bhS + rB + s * 32 + quad * 8];
    }
  }
  const f32x4 zero4 = {0.f, 0.f, 0.f, 0.f};
  f32x4 oA[4], oB[4];
  float mA = -1.0e30f, lA = 0.f, mB = -1.0e30f, lB = 0.f;
#pragma unroll
  for (int nt = 0; nt < 4; ++nt) { oA[nt] = zero4; oB[nt] = zero4; }

  const int sr = tid >> 3, sc8 = tid & 7;
  const int pr = ((sr >> 5) * 2 + ((sr >> 2) & 1)) * 16 + ((sr >> 3) & 3) * 4 + (sr & 3);
  bf16x8 sKh, sKl, sVt;
  auto load_regs = [&](int kc) {
    const int kb = kc * 64;
    sKh = *(const bf16x8*)&KhiG[(long)(kb + sr) * 64 + sc8 * 8];
    sKl = *(const bf16x8*)&KloG[(long)(kb + sr) * 64 + sc8 * 8];
    sVt = *(const bf16x8*)&VtG[(long)sr * 1024 + kb + sc8 * 8];
  };
  auto write_lds = [&](int buf) {
    const int ob = buf * 64 * 72;
    *(bf16x8*)&KhiS[ob + pr * 72 + sc8 * 8] = sKh;
    *(bf16x8*)&KloS[ob + pr * 72 + sc8 * 8] = sKl;
    *(bf16x8*)&VtS[ob + sr * 72 + sc8 * 8] = sVt;
  };
  auto softmax_pack = [&](f32x4 (&sc)[4], f32x4 (&o)[4], float& m_i, float& l_i,
                          int qbw, int kb, bf16x8& pb0, bf16x8& pb1) {
    const int q_glob = qbw + l16;
    if (kb + 63 > qbw) {
#pragma unroll
      for (int ct = 0; ct < 4; ++ct) {
        const int kbase = kb + (ct >> 1) * 32 + quad * 8 + (ct & 1) * 4;
#pragma unroll
        for (int r = 0; r < 4; ++r)
          if (kbase + r > q_glob) sc[ct][r] = -1.0e30f;
      }
    }
    float mx = sc[0][0];
#pragma unroll
    for (int ct = 0; ct < 4; ++ct)
#pragma unroll
      for (int r = 0; r < 4; ++r) mx = fmaxf(mx, sc[ct][r]);
    mx = fmaxf(mx, __shfl_xor(mx, 16));
    mx = fmaxf(mx, __shfl_xor(mx, 32));
    const float mnew = fmaxf(m_i, mx);
    const float alpha = __builtin_amdgcn_exp2f(m_i - mnew);
    m_i = mnew;
    float psum = 0.f;
#pragma unroll
    for (int ct = 0; ct < 4; ++ct)
#pragma unroll
      for (int r = 0; r < 4; ++r) {
        const float pv = __builtin_amdgcn_exp2f(sc[ct][r] - mnew);
        sc[ct][r] = pv;
        psum += pv;
      }
    psum += __shfl_xor(psum, 16);
    psum += __shfl_xor(psum, 32);
    l_i = l_i * alpha + psum;
#pragma unroll
    for (int nt = 0; nt < 4; ++nt)
#pragma unroll
      for (int r = 0; r < 4; ++r) o[nt][r] *= alpha;
#pragma unroll
    for (int c = 0; c < 2; ++c)
#pragma unroll
      for (int r = 0; r < 4; ++r) {
        pb0[c * 4 + r] = (bf16)sc[c][r];
        pb1[c * 4 + r] = (bf16)sc[2 + c][r];
      }
  };
  auto chunk_compute = [&](int kb, int buf) {
    const bool actA = kb <= qbwA + 15;
    const bool actB = kb <= qbwB + 15;
    if (!(actA || actB)) return;
    const int ob = buf * 64 * 72;
    f32x4 scA[4], scB[4];
    __builtin_amdgcn_s_setprio(1);
#pragma unroll
    for (int ct = 0; ct < 4; ++ct) {
      const int krow = ob + (ct * 16 + l16) * 72;
      const bf16x8 kh0 = *(const bf16x8*)&KhiS[krow + quad * 8];
      const bf16x8 kh1 = *(const bf16x8*)&KhiS[krow + 32 + quad * 8];
      const bf16x8 kl0 = *(const bf16x8*)&KloS[krow + quad * 8];
      const bf16x8 kl1 = *(const bf16x8*)&KloS[krow + 32 + quad * 8];
      if (actA) {
        f32x4 s = MFMA16(kh0, qhA[0], zero4);
        s = MFMA16(kh1, qhA[1], s);
        s = MFMA16(kl0, qhA[0], s);
        s = MFMA16(kl1, qhA[1], s);
        s = MFMA16(kh0, qlA[0], s);
        s = MFMA16(kh1, qlA[1], s);
        scA[ct] = s;
      }
      if (actB) {
        f32x4 s = MFMA16(kh0, qhB[0], zero4);
        s = MFMA16(kh1, qhB[1], s);
        s = MFMA16(kl0, qhB[0], s);
        s = MFMA16(kl1, qhB[1], s);
        s = MFMA16(kh0, qlB[0], s);
        s = MFMA16(kh1, qlB[1], s);
        scB[ct] = s;
      }
    }
    __builtin_amdgcn_s_setprio(0);
    bf16x8 pA0, pA1, pB0, pB1;
    if (actA) softmax_pack(scA, oA, mA, lA, qbwA, kb, pA0, pA1);
    if (actB) softmax_pack(scB, oB, mB, lB, qbwB, kb, pB0, pB1);
    __builtin_amdgcn_s_setprio(1);
#pragma unroll
    for (int nt = 0; nt < 4; ++nt) {
      const bf16x8 bv0 = *(const bf16x8*)&VtS[ob + (nt * 16 + l16) * 72 + quad * 8];
      const bf16x8 bv1 = *(const bf16x8*)&VtS[ob + (nt * 16 + l16) * 72 + 32 + quad * 8];
      if (actA) {
        oA[nt] = MFMA16(bv0, pA0, oA[nt]);
        oA[nt] = MFMA16(bv1, pA1, oA[nt]);
      }
      if (actB) {
        oB[nt] = MFMA16(bv0, pB0, oB[nt]);
        oB[nt] = MFMA16(bv1, pB1, oB[nt]);
      }
    }
    __builtin_amdgcn_s_setprio(0);
  };

  const int nch = 2 * (7 - p) + 2;
  load_regs(0);
  write_lds(0);
  __syncthreads();
  for (int kc = 0; kc < nch; ++kc) {
    const int kb = kc * 64;
    const int buf = kc & 1;
    if (kc + 1 < nch) load_regs(kc + 1);
    chunk_compute(kb, buf);
    if (kc + 1 < nch) write_lds(1 - buf);
    __syncthreads();
  }
  {
    const float inv = 1.f / lA;
    const long orow = ((long)b * 1024 + qbwA + l16) * 1024 + hh * 64;
#pragma unroll
    for (int nt = 0; nt < 4; ++nt) {
      bf16x4 v4;
#pragma unroll
      for (int r = 0; r < 4; ++r) v4[r] = (bf16)(oA[nt][r] * inv);
      *(bf16x4*)&Og[orow + nt * 16 + quad * 4] = v4;
    }
  }
  {
    const float inv = 1.f / lB;
    const long orow = ((long)b * 1024 + qbwB + l16) * 1024 + hh * 64;
#pragma unroll
    for (int nt = 0; nt < 4; ++nt) {
      bf16x4 v4;
#pragma unroll
      for (int r = 0; r < 4; ++r) v4[r] = (bf16)(oB[nt][r] * inv);
      *(bf16x4*)&Og[orow + nt * 16 + quad * 4] = v4;
    }
  }
}

extern "C" void kernel_launch(void* const* d_in, const int* in_sizes, int n_in,
                              void* d_out, int out_size, void* d_ws, size_t ws_size,
                              hipStream_t stream) {
  const float* x = (const float*)d_in[0];
  const float* cw = (const float*)d_in[1];
  const int* cidx = (const int*)d_in[2];
  const float* wq = (const float*)d_in[3];
  const int* iq = (const int*)d_in[4];
  const float* wk = (const float*)d_in[5];
  const int* ik = (const int*)d_in[6];
  const float* wv = (const float*)d_in[7];
  const int* iv = (const int*)d_in[8];
  const float* neurons = (const float*)d_in[9];
  const float* pool = (const float*)d_in[10];
  const float* WO = (const float*)d_in[11];
  float* out = (float*)d_out;
  char* ws = (char*)d_ws;
  // Workspace (86 MB peak):
  //   [ 0,16) Khi | [16,32) Klo | [32,48) Vt (all bf16)
  //   [48,64) att bf16
  //   [64,66) WcTh | [66,68) WcTl   bf16 [8][128][1024]
  //   [68,74) Wth  | [74,80) Wtl    bf16 [24][1024][128]
  //   [80,82) hh   | [82,84) hl     bf16 [8][1024][128]
  //   [84,86) WOb bf16
  //   Qhi/Qlo bf16 in d_out (2 x 16 MB), dead before the final f32 write.
  bf16* Khi = (bf16*)(ws + (0l << 20));
  bf16* Klo = (bf16*)(ws + (16l << 20));
  bf16* Vt = (bf16*)(ws + (32l << 20));
  bf16* att = (bf16*)(ws + (48l << 20));
  bf16* WcTh = (bf16*)(ws + (64l << 20));
  bf16* WcTl = (bf16*)(ws + (66l << 20));
  bf16* Wth = (bf16*)(ws + (68l << 20));
  bf16* Wtl = (bf16*)(ws + (74l << 20));
  bf16* hh = (bf16*)(ws + (80l << 20));
  bf16* hl = (bf16*)(ws + (82l << 20));
  bf16* WOb = (bf16*)(ws + (84l << 20));
  bf16* Qhi = (bf16*)d_out;
  bf16* Qlo = (bf16*)d_out + (8l << 20);

  // prep: build+transpose+split Wc (256) + Wn (768) tiles, then cvt (1024)
  k_prep<<<2048, 256, 0, stream>>>(WO, WOb, neurons, cw, cidx, WcTh, WcTl, pool,
                                   wq, iq, wk, ik, wv, iv, Wth, Wtl);
  // h = x * Wc (split A in-kernel, dual B), out split-pair hh/hl [8][1024][128]
  k_gemm_h<<<dim3(2, 16, 8), 256, 0, stream>>>(
      x, WcTh, WcTl, hh, hl, 1024, 128, 1024, 1l << 20, 1l << 17, 1l << 17);
  // Q, K (split-pair, head-split) and V^T (plain) in one launch, 128^2 tiles
  k_gemm_qkv<<<dim3(8, 8, 24), 256, 0, stream>>>(
      hh, hl, Wth, Wtl, Qhi, Qlo, Khi, Klo, Vt, 0.125f * 1.44269504088896f);
  k_attn<<<dim3(4, 128), 512, 0, stream>>>(Qhi, Qlo, Khi, Klo, Vt, att);
  // out(f32, 8192x1024) = att * W_O^T
  k_gemm_bt<128, 128><<<dim3(8, 64, 1), 256, 0, stream>>>(att, WOb, out, 8192, 1024, 1024);
}